// Round 6
// baseline (438.253 us; speedup 1.0000x reference)
//
#include <hip/hip_runtime.h>
#include <hip/hip_bf16.h>

#define NN    20000
#define BB    2
#define EE    320000
#define MROWS (NN * BB)   // 40000

typedef __bf16 bf16x8 __attribute__((ext_vector_type(8)));
typedef __bf16 bf16x4 __attribute__((ext_vector_type(4)));
typedef float  floatx4 __attribute__((ext_vector_type(4)));

// Channel permutation of the 1024 fused output channels (c = head*32+chan):
//   j in [0,512):    c = j>>1;        j even -> k[c], j odd -> v[c]
//   j in [512,1024): c = (j-512)>>1;  j even -> q[c], j odd -> r[c]
// So a uint32 at row*512 + c       = (k[c] | v[c]<<16)  (bf16 pair)
//    a uint32 at row*512 + 256 + c = (q[c] | r[c]<<16)

#define NB_HIST 1250   // (EE+255)/256

// ---------------------------------------------------------------------------
// Merged prep: blocks 0..15 weight transpose+permute, 16 bias+wesum,
// 17..1266 dst histogram. (counts zeroed by hipMemsetAsync beforehand.)
// ---------------------------------------------------------------------------
__global__ __launch_bounds__(256) void prep_kernel(
    const float* __restrict__ Wq, const float* __restrict__ Wk,
    const float* __restrict__ Wv, const float* __restrict__ Wr,
    __hip_bfloat16* __restrict__ wt,
    const float* __restrict__ bq, const float* __restrict__ bk,
    const float* __restrict__ bv, const float* __restrict__ br,
    float* __restrict__ bcat,
    const float* __restrict__ We, float* __restrict__ wesum,
    const int* __restrict__ edst, int* __restrict__ counts) {
  __shared__ float TA[32][65];
  __shared__ float TB[32][65];
  int bt = blockIdx.x;
  int t = threadIdx.x;

  if (bt < 16) {
    const float *A, *B;
    int c0, jbase;
    if (bt < 8) { A = Wk; B = Wv; c0 = 32 * bt;      jbase = 64 * bt; }
    else        { A = Wq; B = Wr; c0 = 32 * (bt-8);  jbase = 512 + 64 * (bt-8); }
    int krow = t >> 2;                   // 0..63
    int cc = (t & 3) * 8;                // 0,8,16,24
    int sel = t >> 7;                    // write phase: 0->A, 1->B
    int u = t & 127;
    int ci = u >> 2;                     // 0..31
    int kk0 = (u & 3) * 16;              // 0,16,32,48

    for (int kt = 0; kt < 4; ++kt) {
      int k = kt * 64 + krow;
      float4 a0 = *(const float4*)(A + (size_t)k * 256 + c0 + cc);
      float4 a1 = *(const float4*)(A + (size_t)k * 256 + c0 + cc + 4);
      float4 b0 = *(const float4*)(B + (size_t)k * 256 + c0 + cc);
      float4 b1 = *(const float4*)(B + (size_t)k * 256 + c0 + cc + 4);
      __syncthreads();                   // previous write phase done
      TA[cc+0][krow]=a0.x; TA[cc+1][krow]=a0.y; TA[cc+2][krow]=a0.z; TA[cc+3][krow]=a0.w;
      TA[cc+4][krow]=a1.x; TA[cc+5][krow]=a1.y; TA[cc+6][krow]=a1.z; TA[cc+7][krow]=a1.w;
      TB[cc+0][krow]=b0.x; TB[cc+1][krow]=b0.y; TB[cc+2][krow]=b0.z; TB[cc+3][krow]=b0.w;
      TB[cc+4][krow]=b1.x; TB[cc+5][krow]=b1.y; TB[cc+6][krow]=b1.z; TB[cc+7][krow]=b1.w;
      __syncthreads();
      float (*T)[65] = sel ? TB : TA;
      int j = jbase + 2 * ci + sel;
      __hip_bfloat16* dst = wt + (size_t)j * 256 + kt * 64 + kk0;
      #pragma unroll
      for (int q = 0; q < 16; ++q) dst[q] = __float2bfloat16(T[ci][kk0 + q]);
    }
  } else if (bt == 16) {
    #pragma unroll
    for (int jj = 0; jj < 4; ++jj) {
      int j = jj * 256 + t;
      float val;
      if (j < 512) { int c = j >> 1;         val = (j & 1) ? bv[c] : bk[c]; }
      else         { int c = (j - 512) >> 1; val = (j & 1) ? br[c] : bq[c]; }
      bcat[j] = val;
    }
    #pragma unroll
    for (int ii = 0; ii < 2; ++ii) {
      int i = ii * 256 + t;
      int h = i >> 6, d = i & 63;
      float s = 0.f;
      for (int c = 0; c < 32; ++c) s += We[(size_t)d * 256 + h * 32 + c];
      wesum[h * 64 + d] = s;
    }
  } else {
    int e = (bt - 17) * 256 + t;
    if (e < EE) atomicAdd(&counts[edst[e]], 1);
  }
}

// ---------------------------------------------------------------------------
// 1-block scan: counts -> offsets/cursor, PLUS degree-balanced permutation.
// perm groups node ids by degree (64-bin counting sort) so that the 4 waves
// of an aggregate block get equal work (kills intra-block straggler drain).
// ---------------------------------------------------------------------------
#define SCAN_PAD (79 * 256)   // 20224 >= NN
__global__ __launch_bounds__(256) void scan_kernel(
    const int* __restrict__ counts,
    int* __restrict__ offsets,
    int* __restrict__ cursor,
    int* __restrict__ perm) {
  __shared__ int lc[SCAN_PAD];
  __shared__ int part[256];
  __shared__ int dh[64];
  int t = threadIdx.x;
  if (t < 64) dh[t] = 0;
  __syncthreads();
  for (int j = 0; j < 79; ++j) {
    int idx = j * 256 + t;
    int c = (idx < NN) ? counts[idx] : 0;
    lc[idx] = c;
    if (idx < NN) atomicAdd(&dh[c < 63 ? c : 63], 1);
  }
  __syncthreads();
  int lo = t * 79;
  int s = 0;
  #pragma unroll 4
  for (int i = 0; i < 79; ++i) s += lc[lo + i];
  part[t] = s;
  __syncthreads();
  for (int off = 1; off < 256; off <<= 1) {
    int v = (t >= off) ? part[t - off] : 0;
    __syncthreads();
    part[t] += v;
    __syncthreads();
  }
  // degree-bin prefix (after all atomics; dh untouched by part-scan)
  if (t == 0) {
    int b = 0;
    for (int i = 0; i < 64; ++i) { int c = dh[i]; dh[i] = b; b += c; }
  }
  int base = (t == 0) ? 0 : part[t - 1];
  for (int i = 0; i < 79; ++i) {
    int c = lc[lo + i];
    lc[lo + i] = base;
    base += c;
  }
  if (t == 255) offsets[NN] = base;
  __syncthreads();
  for (int j = 0; j < 79; ++j) {
    int idx = j * 256 + t;
    if (idx < NN) {
      int v = lc[idx];
      offsets[idx] = v;
      cursor[idx]  = v;
      int c = counts[idx];
      int pos = atomicAdd(&dh[c < 63 ? c : 63], 1);
      perm[pos] = idx;
    }
  }
}

// ---------------------------------------------------------------------------
// Fused scatter + edge-feature reduction: one pass over the edge list.
// Each edge grabs its CSR slot p, writes src there (coalesced read later in
// aggregate) and writes esum[p][h] = edata[e].wesum[h] directly pre-sorted.
// ---------------------------------------------------------------------------
__global__ __launch_bounds__(256) void scatter_esum(
    const int* __restrict__ edst, const int* __restrict__ esrc,
    int* __restrict__ cursor,
    const float* __restrict__ edata, const float* __restrict__ wesum,
    int* __restrict__ ssrc, float* __restrict__ esum) {
  __shared__ float wl[512];
  int t = threadIdx.x;
  wl[t] = wesum[t];
  wl[t + 256] = wesum[t + 256];
  __syncthreads();
  int e = blockIdx.x * 256 + t;        // EE = 1250*256 exactly
  int p = atomicAdd(&cursor[edst[e]], 1);
  ssrc[p] = esrc[e];
  float acc[8] = {};
  const float* row = edata + (size_t)e * 64;
  for (int d = 0; d < 64; d += 4) {
    float4 v = *(const float4*)(row + d);
    #pragma unroll
    for (int hh = 0; hh < 8; ++hh) {
      const float* wv = &wl[hh * 64 + d];
      acc[hh] += v.x * wv[0] + v.y * wv[1] + v.z * wv[2] + v.w * wv[3];
    }
  }
  float* op = esum + (size_t)p * 8;
  *(float4*)op       = make_float4(acc[0], acc[1], acc[2], acc[3]);
  *(float4*)(op + 4) = make_float4(acc[4], acc[5], acc[6], acc[7]);
}

// ---------------------------------------------------------------------------
// Fused q|k|v|r GEMM — A-panel-resident structure.
// Stage the FULL 64-row x 256-K A tile once (fp32 read + in-kernel bf16 cvt,
// 34 KB LDS, ONE barrier per block), then loop the 4 n-panels of 256 cols
// with B fragments read directly from L2 (wt = 0.5 MB, L2-resident).
// A HBM traffic read once (was 4x); no separate xb pass needed.
// LSTR=264: lane stride 528 B -> 2-way LDS banks (free, m136).
// ---------------------------------------------------------------------------
__global__ __launch_bounds__(256) void gemm_qkvr(
    const float* __restrict__ x,     // [MROWS][256] fp32
    const __bf16* __restrict__ wt,   // [1024][256] bf16 (n-major, permuted)
    const float* __restrict__ bcat,  // [1024] permuted
    __hip_bfloat16* __restrict__ out) {  // [MROWS][1024] bf16 permuted
  const int LSTR = 264;
  __shared__ __attribute__((aligned(16))) __bf16 As[64 * LSTR];  // 33.8 KB

  int m0 = blockIdx.x * 64;
  int t = threadIdx.x;
  int w = t >> 6, l = t & 63;
  int lr = l & 15, lq = l >> 4;
  int ar = t >> 2, c0 = (t & 3) * 8;   // staging: row, col base

  // ---- stage A (64 x 256) once ----
  const float* xp = x + (size_t)(m0 + ar) * 256 + c0;
  #pragma unroll
  for (int j = 0; j < 8; ++j) {
    float4 f0 = *(const float4*)(xp + j * 32);
    float4 f1 = *(const float4*)(xp + j * 32 + 4);
    bf16x8 av;
    av[0] = (__bf16)f0.x; av[1] = (__bf16)f0.y;
    av[2] = (__bf16)f0.z; av[3] = (__bf16)f0.w;
    av[4] = (__bf16)f1.x; av[5] = (__bf16)f1.y;
    av[6] = (__bf16)f1.z; av[7] = (__bf16)f1.w;
    *(bf16x8*)&As[ar * LSTR + c0 + j * 32] = av;
  }
  __syncthreads();

  // ---- 4 n-panels of 256 columns ----
  #pragma unroll 1
  for (int p = 0; p < 4; ++p) {
    int n0 = p * 256;
    floatx4 acc[4][4] = {};            // [mt][nt]
    const __bf16* wbase = wt + (size_t)(n0 + 64 * w + lr) * 256 + lq * 8;
    #pragma unroll
    for (int ks = 0; ks < 4; ++ks) {
      bf16x8 bfr[2][4];
      #pragma unroll
      for (int kk = 0; kk < 2; ++kk)
        #pragma unroll
        for (int nt = 0; nt < 4; ++nt)
          bfr[kk][nt] = *(const bf16x8*)(wbase + (size_t)nt * 16 * 256 + ks * 64 + kk * 32);
      #pragma unroll
      for (int kk = 0; kk < 2; ++kk) {
        bf16x8 af[4];
        #pragma unroll
        for (int mt = 0; mt < 4; ++mt)
          af[mt] = *(const bf16x8*)&As[(16 * mt + lr) * LSTR + ks * 64 + kk * 32 + lq * 8];
        #pragma unroll
        for (int mt = 0; mt < 4; ++mt)
          #pragma unroll
          for (int nt = 0; nt < 4; ++nt)
            acc[mt][nt] = __builtin_amdgcn_mfma_f32_16x16x32_bf16(af[mt], bfr[kk][nt], acc[mt][nt], 0, 0, 0);
      }
    }
    // C/D: col = lane&15, row = (lane>>4)*4 + reg
    #pragma unroll
    for (int mt = 0; mt < 4; ++mt)
      #pragma unroll
      for (int nt = 0; nt < 4; ++nt)
        #pragma unroll
        for (int r = 0; r < 4; ++r) {
          int gr = m0 + 16 * mt + lq * 4 + r;
          int gc = n0 + 64 * w + 16 * nt + lr;
          out[(size_t)gr * 1024 + gc] = __float2bfloat16(acc[mt][nt][r] + bcat[gc]);
        }
  }
}

// ---------------------------------------------------------------------------
// Fused logits + softmax + V-aggregation + residual, fp32 out.
// ONE WAVE per (dst,b); nodes assigned via degree-sorted perm so all 4
// waves of a block carry equal work (no intra-block straggler drain).
// Depth-6 software pipeline: 6 dwordx4 kv-gathers + 6 esum loads in flight.
// No online-max (logits bounded, exp() direct).
// ---------------------------------------------------------------------------
#define LOADSLOT(KV, EV, IDX)                                        \
  { int s_ = __builtin_amdgcn_readlane(s_l, (IDX));                  \
    KV = *(const uint4*)(kvl + (size_t)s_ * 1024);                   \
    EV = esp[(size_t)(IDX) * 8]; }

#define CONSUME(KV, EV)                                              \
  { float part = __uint_as_float(KV.x << 16) * q0                    \
               + __uint_as_float(KV.y << 16) * q1                    \
               + __uint_as_float(KV.z << 16) * q2                    \
               + __uint_as_float(KV.w << 16) * q3;                   \
    part += __shfl_xor(part, 1, 64);                                 \
    part += __shfl_xor(part, 2, 64);                                 \
    part += __shfl_xor(part, 4, 64);                                 \
    float p = __expf(part * 0.17677669529663687f + EV);              \
    z += p;                                                          \
    a0 += p * __uint_as_float(KV.x & 0xFFFF0000u);                   \
    a1 += p * __uint_as_float(KV.y & 0xFFFF0000u);                   \
    a2 += p * __uint_as_float(KV.z & 0xFFFF0000u);                   \
    a3 += p * __uint_as_float(KV.w & 0xFFFF0000u); }

__global__ __launch_bounds__(256) void aggregate_kernel(
    const unsigned int* __restrict__ qkvr,  // [MROWS][512] uints (kv | qr pairs)
    const float* __restrict__ esum,         // [E][8] CSR order
    const int* __restrict__ offsets,
    const int* __restrict__ ssrc,           // [E] src in CSR order
    const int* __restrict__ perm,           // [NN] degree-sorted node ids
    float* __restrict__ out) {              // [MROWS][256] fp32
  int t = threadIdx.x;
  int w = t >> 6, l = t & 63;
  int idx = blockIdx.x * 4 + w;             // grid 10000 -> 40000 waves
  int n = perm[idx >> 1];
  int b = idx & 1;
  int nb = 2 * n + b;
  int h = l >> 3;
  int beg = offsets[n], end = offsets[n + 1];

  uint4 qr4 = *(const uint4*)(qkvr + (size_t)nb * 512 + 256 + l * 4);
  float q0 = __uint_as_float(qr4.x << 16), q1 = __uint_as_float(qr4.y << 16);
  float q2 = __uint_as_float(qr4.z << 16), q3 = __uint_as_float(qr4.w << 16);

  const unsigned* kvl = qkvr + (size_t)b * 512 + l * 4;  // + s*1024 per edge

  float z = 0.f, a0 = 0.f, a1 = 0.f, a2 = 0.f, a3 = 0.f;

  for (int base = beg; base < end; base += 64) {
    int chunk = min(64, end - base);
    int s_l = (l < chunk) ? ssrc[base + l] : 0;
    const float* esp = esum + (size_t)base * 8 + h;
    uint4 k0 = {0,0,0,0}, k1 = {0,0,0,0}, k2 = {0,0,0,0};
    uint4 k3 = {0,0,0,0}, k4 = {0,0,0,0}, k5 = {0,0,0,0};
    float e0 = 0.f, e1 = 0.f, e2 = 0.f, e3 = 0.f, e4 = 0.f, e5 = 0.f;
    LOADSLOT(k0, e0, 0);
    if (chunk > 1) LOADSLOT(k1, e1, 1);
    if (chunk > 2) LOADSLOT(k2, e2, 2);
    if (chunk > 3) LOADSLOT(k3, e3, 3);
    if (chunk > 4) LOADSLOT(k4, e4, 4);
    if (chunk > 5) LOADSLOT(k5, e5, 5);
    for (int i = 0; i < chunk; i += 6) {
      CONSUME(k0, e0);
      if (i + 6 < chunk) LOADSLOT(k0, e0, i + 6);
      if (i + 1 < chunk) {
        CONSUME(k1, e1);
        if (i + 7 < chunk) LOADSLOT(k1, e1, i + 7);
        if (i + 2 < chunk) {
          CONSUME(k2, e2);
          if (i + 8 < chunk) LOADSLOT(k2, e2, i + 8);
          if (i + 3 < chunk) {
            CONSUME(k3, e3);
            if (i + 9 < chunk) LOADSLOT(k3, e3, i + 9);
            if (i + 4 < chunk) {
              CONSUME(k4, e4);
              if (i + 10 < chunk) LOADSLOT(k4, e4, i + 10);
              if (i + 5 < chunk) {
                CONSUME(k5, e5);
                if (i + 11 < chunk) LOADSLOT(k5, e5, i + 11);
              }
            }
          }
        }
      }
    }
  }
  float inv = (z > 0.f) ? (1.0f / z) : 0.f;
  float4 o = make_float4(a0 * inv + __uint_as_float(qr4.x & 0xFFFF0000u),
                         a1 * inv + __uint_as_float(qr4.y & 0xFFFF0000u),
                         a2 * inv + __uint_as_float(qr4.z & 0xFFFF0000u),
                         a3 * inv + __uint_as_float(qr4.w & 0xFFFF0000u));
  *(float4*)(out + (size_t)nb * 256 + l * 4) = o;
}

// ---------------------------------------------------------------------------
extern "C" void kernel_launch(void* const* d_in, const int* in_sizes, int n_in,
                              void* d_out, int out_size, void* d_ws, size_t ws_size,
                              hipStream_t stream) {
  (void)in_sizes; (void)n_in; (void)out_size; (void)ws_size;
  const float* x     = (const float*)d_in[0];
  const float* edata = (const float*)d_in[1];
  const int* esrc    = (const int*)d_in[2];
  const int* edst    = (const int*)d_in[3];
  const float* Wq    = (const float*)d_in[4];
  const float* bq    = (const float*)d_in[5];
  const float* Wk    = (const float*)d_in[6];
  const float* bk    = (const float*)d_in[7];
  const float* Wv    = (const float*)d_in[8];
  const float* bv    = (const float*)d_in[9];
  const float* We    = (const float*)d_in[10];
  const float* Wr    = (const float*)d_in[11];
  const float* br    = (const float*)d_in[12];
  float* out = (float*)d_out;     // fp32 output

  char* ws = (char*)d_ws;
  size_t off = 0;
  auto carve = [&](size_t bytes) -> void* {
    void* p = ws + off;
    off += (bytes + 255) & ~(size_t)255;
    return p;
  };
  int* counts    = (int*)carve((size_t)NN * 4);
  int* offsets   = (int*)carve((size_t)(NN + 1) * 4);
  int* cursor    = (int*)carve((size_t)NN * 4);
  int* perm      = (int*)carve((size_t)NN * 4);
  int* ssrc      = (int*)carve((size_t)EE * 4);               // 1.28 MB
  __hip_bfloat16* wt = (__hip_bfloat16*)carve((size_t)1024 * 256 * 2);
  float* bcat    = (float*)carve(1024 * 4);
  float* wesum   = (float*)carve(8 * 64 * 4);
  float* esum    = (float*)carve((size_t)EE * 8 * 4);         // 10.24 MB
  __hip_bfloat16* qkvr = (__hip_bfloat16*)carve((size_t)MROWS * 1024 * 2); // 81.9 MB

  hipMemsetAsync(counts, 0, (size_t)NN * 4, stream);
  prep_kernel<<<17 + NB_HIST, 256, 0, stream>>>(
      Wq, Wk, Wv, Wr, wt, bq, bk, bv, br, bcat, We, wesum, edst, counts);
  scan_kernel<<<1, 256, 0, stream>>>(counts, offsets, cursor, perm);
  scatter_esum<<<EE / 256, 256, 0, stream>>>(edst, esrc, cursor, edata, wesum,
                                             ssrc, esum);
  gemm_qkvr<<<MROWS / 64, 256, 0, stream>>>(x, (const __bf16*)wt, bcat, qkvr);
  aggregate_kernel<<<MROWS / 4, 256, 0, stream>>>((const unsigned int*)qkvr, esum,
                                                  offsets, ssrc, perm, out);
}

// Round 7
// 410.842 us; speedup vs baseline: 1.0667x; 1.0667x over previous
//
#include <hip/hip_runtime.h>
#include <hip/hip_bf16.h>

#define NN    20000
#define BB    2
#define EE    320000
#define MROWS (NN * BB)   // 40000

typedef __bf16 bf16x8 __attribute__((ext_vector_type(8)));
typedef __bf16 bf16x4 __attribute__((ext_vector_type(4)));
typedef float  floatx4 __attribute__((ext_vector_type(4)));

// Channel permutation of the 1024 fused output channels (c = head*32+chan):
//   j in [0,512):    c = j>>1;        j even -> k[c], j odd -> v[c]
//   j in [512,1024): c = (j-512)>>1;  j even -> q[c], j odd -> r[c]
// So a uint32 at row*512 + c       = (k[c] | v[c]<<16)  (bf16 pair)
//    a uint32 at row*512 + 256 + c = (q[c] | r[c]<<16)

#define NB_HIST 1250   // (EE+255)/256
#define NB_CVT  1250   // MROWS*256 / 8192

// ---------------------------------------------------------------------------
// Merged prep: blocks 0..15 weight transpose+permute, 16 bias+wesum,
// 17..1266 dst histogram, 1267..2516 x -> bf16 convert.
// (counts zeroed by hipMemsetAsync beforehand.)
// ---------------------------------------------------------------------------
__global__ __launch_bounds__(256) void prep_kernel(
    const float* __restrict__ Wq, const float* __restrict__ Wk,
    const float* __restrict__ Wv, const float* __restrict__ Wr,
    __hip_bfloat16* __restrict__ wt,
    const float* __restrict__ bq, const float* __restrict__ bk,
    const float* __restrict__ bv, const float* __restrict__ br,
    float* __restrict__ bcat,
    const float* __restrict__ We, float* __restrict__ wesum,
    const int* __restrict__ edst, int* __restrict__ counts,
    const float* __restrict__ x, __bf16* __restrict__ xb) {
  __shared__ float TA[32][65];
  __shared__ float TB[32][65];
  int bt = blockIdx.x;
  int t = threadIdx.x;

  if (bt < 16) {
    const float *A, *B;
    int c0, jbase;
    if (bt < 8) { A = Wk; B = Wv; c0 = 32 * bt;      jbase = 64 * bt; }
    else        { A = Wq; B = Wr; c0 = 32 * (bt-8);  jbase = 512 + 64 * (bt-8); }
    int krow = t >> 2;                   // 0..63
    int cc = (t & 3) * 8;                // 0,8,16,24
    int sel = t >> 7;                    // write phase: 0->A, 1->B
    int u = t & 127;
    int ci = u >> 2;                     // 0..31
    int kk0 = (u & 3) * 16;              // 0,16,32,48

    for (int kt = 0; kt < 4; ++kt) {
      int k = kt * 64 + krow;
      float4 a0 = *(const float4*)(A + (size_t)k * 256 + c0 + cc);
      float4 a1 = *(const float4*)(A + (size_t)k * 256 + c0 + cc + 4);
      float4 b0 = *(const float4*)(B + (size_t)k * 256 + c0 + cc);
      float4 b1 = *(const float4*)(B + (size_t)k * 256 + c0 + cc + 4);
      __syncthreads();                   // previous write phase done
      TA[cc+0][krow]=a0.x; TA[cc+1][krow]=a0.y; TA[cc+2][krow]=a0.z; TA[cc+3][krow]=a0.w;
      TA[cc+4][krow]=a1.x; TA[cc+5][krow]=a1.y; TA[cc+6][krow]=a1.z; TA[cc+7][krow]=a1.w;
      TB[cc+0][krow]=b0.x; TB[cc+1][krow]=b0.y; TB[cc+2][krow]=b0.z; TB[cc+3][krow]=b0.w;
      TB[cc+4][krow]=b1.x; TB[cc+5][krow]=b1.y; TB[cc+6][krow]=b1.z; TB[cc+7][krow]=b1.w;
      __syncthreads();
      float (*T)[65] = sel ? TB : TA;
      int j = jbase + 2 * ci + sel;
      __hip_bfloat16* dst = wt + (size_t)j * 256 + kt * 64 + kk0;
      #pragma unroll
      for (int q = 0; q < 16; ++q) dst[q] = __float2bfloat16(T[ci][kk0 + q]);
    }
  } else if (bt == 16) {
    #pragma unroll
    for (int jj = 0; jj < 4; ++jj) {
      int j = jj * 256 + t;
      float val;
      if (j < 512) { int c = j >> 1;         val = (j & 1) ? bv[c] : bk[c]; }
      else         { int c = (j - 512) >> 1; val = (j & 1) ? br[c] : bq[c]; }
      bcat[j] = val;
    }
    #pragma unroll
    for (int ii = 0; ii < 2; ++ii) {
      int i = ii * 256 + t;
      int h = i >> 6, d = i & 63;
      float s = 0.f;
      for (int c = 0; c < 32; ++c) s += We[(size_t)d * 256 + h * 32 + c];
      wesum[h * 64 + d] = s;
    }
  } else if (bt < 17 + NB_HIST) {
    int e = (bt - 17) * 256 + t;
    if (e < EE) atomicAdd(&counts[edst[e]], 1);
  } else {
    int cb = bt - 17 - NB_HIST;          // 0..1249
    size_t base = (size_t)cb * 8192 + t * 4;
    #pragma unroll
    for (int j = 0; j < 8; ++j) {
      float4 v = *(const float4*)(x + base + j * 1024);
      bf16x4 o;
      o[0] = (__bf16)v.x; o[1] = (__bf16)v.y;
      o[2] = (__bf16)v.z; o[3] = (__bf16)v.w;
      *(bf16x4*)(xb + base + j * 1024) = o;
    }
  }
}

// ---------------------------------------------------------------------------
// 1-block scan of counts -> offsets, cursor. Counts staged through LDS so
// every global access is coalesced.
// ---------------------------------------------------------------------------
#define SCAN_PAD (79 * 256)   // 20224 >= NN
__global__ __launch_bounds__(256) void scan_kernel(
    const int* __restrict__ counts,
    int* __restrict__ offsets,
    int* __restrict__ cursor) {
  __shared__ int lc[SCAN_PAD];
  __shared__ int part[256];
  int t = threadIdx.x;
  for (int j = 0; j < 79; ++j) {
    int idx = j * 256 + t;
    lc[idx] = (idx < NN) ? counts[idx] : 0;
  }
  __syncthreads();
  int lo = t * 79;
  int s = 0;
  #pragma unroll 4
  for (int i = 0; i < 79; ++i) s += lc[lo + i];
  part[t] = s;
  __syncthreads();
  for (int off = 1; off < 256; off <<= 1) {
    int v = (t >= off) ? part[t - off] : 0;
    __syncthreads();
    part[t] += v;
    __syncthreads();
  }
  int base = (t == 0) ? 0 : part[t - 1];
  for (int i = 0; i < 79; ++i) {
    int c = lc[lo + i];
    lc[lo + i] = base;
    base += c;
  }
  if (t == 255) offsets[NN] = base;
  __syncthreads();
  for (int j = 0; j < 79; ++j) {
    int idx = j * 256 + t;
    if (idx < NN) {
      int v = lc[idx];
      offsets[idx] = v;
      cursor[idx]  = v;
    }
  }
}

// ---------------------------------------------------------------------------
// Fused scatter + edge-feature reduction: one pass over the edge list.
// Each edge grabs its CSR slot p, writes src there (coalesced read later in
// aggregate) and writes esum[p][h] = edata[e].wesum[h] directly pre-sorted.
// ---------------------------------------------------------------------------
__global__ __launch_bounds__(256) void scatter_esum(
    const int* __restrict__ edst, const int* __restrict__ esrc,
    int* __restrict__ cursor,
    const float* __restrict__ edata, const float* __restrict__ wesum,
    int* __restrict__ ssrc, float* __restrict__ esum) {
  __shared__ float wl[512];
  int t = threadIdx.x;
  wl[t] = wesum[t];
  wl[t + 256] = wesum[t + 256];
  __syncthreads();
  int e = blockIdx.x * 256 + t;        // EE = 1250*256 exactly
  int p = atomicAdd(&cursor[edst[e]], 1);
  ssrc[p] = esrc[e];
  float acc[8] = {};
  const float* row = edata + (size_t)e * 64;
  for (int d = 0; d < 64; d += 4) {
    float4 v = *(const float4*)(row + d);
    #pragma unroll
    for (int hh = 0; hh < 8; ++hh) {
      const float* wv = &wl[hh * 64 + d];
      acc[hh] += v.x * wv[0] + v.y * wv[1] + v.z * wv[2] + v.w * wv[3];
    }
  }
  float* op = esum + (size_t)p * 8;
  *(float4*)op       = make_float4(acc[0], acc[1], acc[2], acc[3]);
  *(float4*)(op + 4) = make_float4(acc[4], acc[5], acc[6], acc[7]);
}

// ---------------------------------------------------------------------------
// Fused q|k|v|r GEMM — BARRIER-FREE, LDS-FREE. Both operands read directly
// from L2 into registers as 16 B/lane fragments:
//   A (xb, bf16): 16 lanes (lr) x 4 cols (lq) -> 16 dense 64-B lines/load
//   B (wt, 0.5 MB L2-resident): identical pattern.
// No __syncthreads anywhere -> compiler freely software-pipelines the 4
// K-steps. Block swizzle keeps the 4 n-panels of one m-tile at bid==const
// (mod 8) so they share the A panel within one XCD's L2.
// Tile 64x256, 4 waves each 64x64 (4x4 frags of 16x16x32).
// ---------------------------------------------------------------------------
__global__ __launch_bounds__(256) void gemm_qkvr(
    const __bf16* __restrict__ xb,   // [MROWS][256] bf16
    const __bf16* __restrict__ wt,   // [1024][256] bf16 (n-major, permuted)
    const float* __restrict__ bcat,  // [1024] permuted
    __hip_bfloat16* __restrict__ out) {  // [MROWS][1024] bf16 permuted
  int bid = blockIdx.x;              // 0..2499
  int g, p;
  if (bid >= 2496) { g = 624; p = bid - 2496; }          // tail m-tile
  else { g = ((bid >> 5) << 3) | (bid & 7); p = (bid >> 3) & 3; }
  int m0 = g * 64;
  int n0 = p * 256;
  int t = threadIdx.x;
  int w = t >> 6, l = t & 63;
  int lr = l & 15, lq = l >> 4;

  const __bf16* abase = xb + (size_t)(m0 + lr) * 256 + lq * 8;
  const __bf16* wbase = wt + (size_t)(n0 + 64 * w + lr) * 256 + lq * 8;

  floatx4 acc[4][4] = {};            // [mt][nt]

  #pragma unroll
  for (int ks = 0; ks < 4; ++ks) {
    bf16x8 af[2][4], bfr[2][4];
    #pragma unroll
    for (int kk = 0; kk < 2; ++kk)
      #pragma unroll
      for (int mt = 0; mt < 4; ++mt)
        af[kk][mt] = *(const bf16x8*)(abase + (size_t)mt * 16 * 256 + ks * 64 + kk * 32);
    #pragma unroll
    for (int kk = 0; kk < 2; ++kk)
      #pragma unroll
      for (int nt = 0; nt < 4; ++nt)
        bfr[kk][nt] = *(const bf16x8*)(wbase + (size_t)nt * 16 * 256 + ks * 64 + kk * 32);
    #pragma unroll
    for (int kk = 0; kk < 2; ++kk)
      #pragma unroll
      for (int mt = 0; mt < 4; ++mt)
        #pragma unroll
        for (int nt = 0; nt < 4; ++nt)
          acc[mt][nt] = __builtin_amdgcn_mfma_f32_16x16x32_bf16(af[kk][mt], bfr[kk][nt], acc[mt][nt], 0, 0, 0);
  }

  // C/D: col = lane&15, row = (lane>>4)*4 + reg
  #pragma unroll
  for (int mt = 0; mt < 4; ++mt)
    #pragma unroll
    for (int nt = 0; nt < 4; ++nt)
      #pragma unroll
      for (int r = 0; r < 4; ++r) {
        int gr = m0 + 16 * mt + (l >> 4) * 4 + r;
        int gc = n0 + 64 * w + 16 * nt + lr;
        out[(size_t)gr * 1024 + gc] = __float2bfloat16(acc[mt][nt][r] + bcat[gc]);
      }
}

// ---------------------------------------------------------------------------
// Fused logits + softmax + V-aggregation + residual, fp32 out.
// ONE WAVE per (dst,b) — 40000 waves; lane l owns channels 4l..4l+3
// (head h = l>>3). Depth-6 software pipeline: 6 dwordx4 kv-gathers + 6
// esum loads in flight per wave; all guards wave-uniform. No online-max
// (logits bounded, exp() direct).
// ---------------------------------------------------------------------------
#define LOADSLOT(KV, EV, IDX)                                        \
  { int s_ = __builtin_amdgcn_readlane(s_l, (IDX));                  \
    KV = *(const uint4*)(kvl + (size_t)s_ * 1024);                   \
    EV = esp[(size_t)(IDX) * 8]; }

#define CONSUME(KV, EV)                                              \
  { float part = __uint_as_float(KV.x << 16) * q0                    \
               + __uint_as_float(KV.y << 16) * q1                    \
               + __uint_as_float(KV.z << 16) * q2                    \
               + __uint_as_float(KV.w << 16) * q3;                   \
    part += __shfl_xor(part, 1, 64);                                 \
    part += __shfl_xor(part, 2, 64);                                 \
    part += __shfl_xor(part, 4, 64);                                 \
    float p = __expf(part * 0.17677669529663687f + EV);              \
    z += p;                                                          \
    a0 += p * __uint_as_float(KV.x & 0xFFFF0000u);                   \
    a1 += p * __uint_as_float(KV.y & 0xFFFF0000u);                   \
    a2 += p * __uint_as_float(KV.z & 0xFFFF0000u);                   \
    a3 += p * __uint_as_float(KV.w & 0xFFFF0000u); }

__global__ __launch_bounds__(256) void aggregate_kernel(
    const unsigned int* __restrict__ qkvr,  // [MROWS][512] uints (kv | qr pairs)
    const float* __restrict__ esum,         // [E][8] CSR order
    const int* __restrict__ offsets,
    const int* __restrict__ ssrc,           // [E] src in CSR order
    float* __restrict__ out) {              // [MROWS][256] fp32
  int t = threadIdx.x;
  int w = t >> 6, l = t & 63;
  int nb = blockIdx.x * 4 + w;              // grid 10000 -> 40000 waves
  int b = nb & 1, n = nb >> 1;
  int h = l >> 3;
  int beg = offsets[n], end = offsets[n + 1];

  uint4 qr4 = *(const uint4*)(qkvr + (size_t)nb * 512 + 256 + l * 4);
  float q0 = __uint_as_float(qr4.x << 16), q1 = __uint_as_float(qr4.y << 16);
  float q2 = __uint_as_float(qr4.z << 16), q3 = __uint_as_float(qr4.w << 16);

  const unsigned* kvl = qkvr + (size_t)b * 512 + l * 4;  // + s*1024 per edge

  float z = 0.f, a0 = 0.f, a1 = 0.f, a2 = 0.f, a3 = 0.f;

  for (int base = beg; base < end; base += 64) {
    int chunk = min(64, end - base);
    int s_l = (l < chunk) ? ssrc[base + l] : 0;
    const float* esp = esum + (size_t)base * 8 + h;
    uint4 k0 = {0,0,0,0}, k1 = {0,0,0,0}, k2 = {0,0,0,0};
    uint4 k3 = {0,0,0,0}, k4 = {0,0,0,0}, k5 = {0,0,0,0};
    float e0 = 0.f, e1 = 0.f, e2 = 0.f, e3 = 0.f, e4 = 0.f, e5 = 0.f;
    LOADSLOT(k0, e0, 0);
    if (chunk > 1) LOADSLOT(k1, e1, 1);
    if (chunk > 2) LOADSLOT(k2, e2, 2);
    if (chunk > 3) LOADSLOT(k3, e3, 3);
    if (chunk > 4) LOADSLOT(k4, e4, 4);
    if (chunk > 5) LOADSLOT(k5, e5, 5);
    for (int i = 0; i < chunk; i += 6) {
      CONSUME(k0, e0);
      if (i + 6 < chunk) LOADSLOT(k0, e0, i + 6);
      if (i + 1 < chunk) {
        CONSUME(k1, e1);
        if (i + 7 < chunk) LOADSLOT(k1, e1, i + 7);
        if (i + 2 < chunk) {
          CONSUME(k2, e2);
          if (i + 8 < chunk) LOADSLOT(k2, e2, i + 8);
          if (i + 3 < chunk) {
            CONSUME(k3, e3);
            if (i + 9 < chunk) LOADSLOT(k3, e3, i + 9);
            if (i + 4 < chunk) {
              CONSUME(k4, e4);
              if (i + 10 < chunk) LOADSLOT(k4, e4, i + 10);
              if (i + 5 < chunk) {
                CONSUME(k5, e5);
                if (i + 11 < chunk) LOADSLOT(k5, e5, i + 11);
              }
            }
          }
        }
      }
    }
  }
  float inv = (z > 0.f) ? (1.0f / z) : 0.f;
  float4 o = make_float4(a0 * inv + __uint_as_float(qr4.x & 0xFFFF0000u),
                         a1 * inv + __uint_as_float(qr4.y & 0xFFFF0000u),
                         a2 * inv + __uint_as_float(qr4.z & 0xFFFF0000u),
                         a3 * inv + __uint_as_float(qr4.w & 0xFFFF0000u));
  *(float4*)(out + (size_t)nb * 256 + l * 4) = o;
}

// ---------------------------------------------------------------------------
extern "C" void kernel_launch(void* const* d_in, const int* in_sizes, int n_in,
                              void* d_out, int out_size, void* d_ws, size_t ws_size,
                              hipStream_t stream) {
  (void)in_sizes; (void)n_in; (void)out_size; (void)ws_size;
  const float* x     = (const float*)d_in[0];
  const float* edata = (const float*)d_in[1];
  const int* esrc    = (const int*)d_in[2];
  const int* edst    = (const int*)d_in[3];
  const float* Wq    = (const float*)d_in[4];
  const float* bq    = (const float*)d_in[5];
  const float* Wk    = (const float*)d_in[6];
  const float* bk    = (const float*)d_in[7];
  const float* Wv    = (const float*)d_in[8];
  const float* bv    = (const float*)d_in[9];
  const float* We    = (const float*)d_in[10];
  const float* Wr    = (const float*)d_in[11];
  const float* br    = (const float*)d_in[12];
  float* out = (float*)d_out;     // fp32 output

  char* ws = (char*)d_ws;
  size_t off = 0;
  auto carve = [&](size_t bytes) -> void* {
    void* p = ws + off;
    off += (bytes + 255) & ~(size_t)255;
    return p;
  };
  int* counts    = (int*)carve((size_t)NN * 4);
  int* offsets   = (int*)carve((size_t)(NN + 1) * 4);
  int* cursor    = (int*)carve((size_t)NN * 4);
  int* ssrc      = (int*)carve((size_t)EE * 4);               // 1.28 MB
  __hip_bfloat16* wt = (__hip_bfloat16*)carve((size_t)1024 * 256 * 2);
  float* bcat    = (float*)carve(1024 * 4);
  float* wesum   = (float*)carve(8 * 64 * 4);
  float* esum    = (float*)carve((size_t)EE * 8 * 4);         // 10.24 MB
  __bf16* xb     = (__bf16*)carve((size_t)MROWS * 256 * 2);   // 20.5 MB
  __hip_bfloat16* qkvr = (__hip_bfloat16*)carve((size_t)MROWS * 1024 * 2); // 81.9 MB

  hipMemsetAsync(counts, 0, (size_t)NN * 4, stream);
  prep_kernel<<<17 + NB_HIST + NB_CVT, 256, 0, stream>>>(
      Wq, Wk, Wv, Wr, wt, bq, bk, bv, br, bcat, We, wesum, edst, counts, x, xb);
  scan_kernel<<<1, 256, 0, stream>>>(counts, offsets, cursor);
  scatter_esum<<<EE / 256, 256, 0, stream>>>(edst, esrc, cursor, edata, wesum,
                                             ssrc, esum);
  gemm_qkvr<<<2500, 256, 0, stream>>>(xb, (const __bf16*)wt, bcat, qkvr);
  aggregate_kernel<<<MROWS / 4, 256, 0, stream>>>((const unsigned int*)qkvr, esum,
                                                  offsets, ssrc, out);
}

// Round 8
// 376.474 us; speedup vs baseline: 1.1641x; 1.0913x over previous
//
#include <hip/hip_runtime.h>
#include <hip/hip_bf16.h>

#define NN    20000
#define BB    2
#define EE    320000
#define MROWS (NN * BB)   // 40000

typedef __bf16 bf16x8 __attribute__((ext_vector_type(8)));
typedef __bf16 bf16x4 __attribute__((ext_vector_type(4)));
typedef float  floatx4 __attribute__((ext_vector_type(4)));

// Channel permutation of the 1024 fused output channels (c = head*32+chan):
//   j in [0,512):    c = j>>1;        j even -> k[c], j odd -> v[c]
//   j in [512,1024): c = (j-512)>>1;  j even -> q[c], j odd -> r[c]
// So a uint32 at row*512 + c       = (k[c] | v[c]<<16)  (bf16 pair)
//    a uint32 at row*512 + 256 + c = (q[c] | r[c]<<16)

#define NB_HIST 1250   // (EE+255)/256
#define NB_CVT  1250   // MROWS*256 / 8192

// ---------------------------------------------------------------------------
// Merged prep: blocks 0..15 weight transpose+permute, 16 bias+wesum,
// 17..1266 dst histogram, 1267..2516 x -> bf16 convert.
// (counts zeroed by hipMemsetAsync beforehand.)
// ---------------------------------------------------------------------------
__global__ __launch_bounds__(256) void prep_kernel(
    const float* __restrict__ Wq, const float* __restrict__ Wk,
    const float* __restrict__ Wv, const float* __restrict__ Wr,
    __hip_bfloat16* __restrict__ wt,
    const float* __restrict__ bq, const float* __restrict__ bk,
    const float* __restrict__ bv, const float* __restrict__ br,
    float* __restrict__ bcat,
    const float* __restrict__ We, float* __restrict__ wesum,
    const int* __restrict__ edst, int* __restrict__ counts,
    const float* __restrict__ x, __bf16* __restrict__ xb) {
  __shared__ float TA[32][65];
  __shared__ float TB[32][65];
  int bt = blockIdx.x;
  int t = threadIdx.x;

  if (bt < 16) {
    const float *A, *B;
    int c0, jbase;
    if (bt < 8) { A = Wk; B = Wv; c0 = 32 * bt;      jbase = 64 * bt; }
    else        { A = Wq; B = Wr; c0 = 32 * (bt-8);  jbase = 512 + 64 * (bt-8); }
    int krow = t >> 2;                   // 0..63
    int cc = (t & 3) * 8;                // 0,8,16,24
    int sel = t >> 7;                    // write phase: 0->A, 1->B
    int u = t & 127;
    int ci = u >> 2;                     // 0..31
    int kk0 = (u & 3) * 16;              // 0,16,32,48

    for (int kt = 0; kt < 4; ++kt) {
      int k = kt * 64 + krow;
      float4 a0 = *(const float4*)(A + (size_t)k * 256 + c0 + cc);
      float4 a1 = *(const float4*)(A + (size_t)k * 256 + c0 + cc + 4);
      float4 b0 = *(const float4*)(B + (size_t)k * 256 + c0 + cc);
      float4 b1 = *(const float4*)(B + (size_t)k * 256 + c0 + cc + 4);
      __syncthreads();                   // previous write phase done
      TA[cc+0][krow]=a0.x; TA[cc+1][krow]=a0.y; TA[cc+2][krow]=a0.z; TA[cc+3][krow]=a0.w;
      TA[cc+4][krow]=a1.x; TA[cc+5][krow]=a1.y; TA[cc+6][krow]=a1.z; TA[cc+7][krow]=a1.w;
      TB[cc+0][krow]=b0.x; TB[cc+1][krow]=b0.y; TB[cc+2][krow]=b0.z; TB[cc+3][krow]=b0.w;
      TB[cc+4][krow]=b1.x; TB[cc+5][krow]=b1.y; TB[cc+6][krow]=b1.z; TB[cc+7][krow]=b1.w;
      __syncthreads();
      float (*T)[65] = sel ? TB : TA;
      int j = jbase + 2 * ci + sel;
      __hip_bfloat16* dst = wt + (size_t)j * 256 + kt * 64 + kk0;
      #pragma unroll
      for (int q = 0; q < 16; ++q) dst[q] = __float2bfloat16(T[ci][kk0 + q]);
    }
  } else if (bt == 16) {
    #pragma unroll
    for (int jj = 0; jj < 4; ++jj) {
      int j = jj * 256 + t;
      float val;
      if (j < 512) { int c = j >> 1;         val = (j & 1) ? bv[c] : bk[c]; }
      else         { int c = (j - 512) >> 1; val = (j & 1) ? br[c] : bq[c]; }
      bcat[j] = val;
    }
    #pragma unroll
    for (int ii = 0; ii < 2; ++ii) {
      int i = ii * 256 + t;
      int h = i >> 6, d = i & 63;
      float s = 0.f;
      for (int c = 0; c < 32; ++c) s += We[(size_t)d * 256 + h * 32 + c];
      wesum[h * 64 + d] = s;
    }
  } else if (bt < 17 + NB_HIST) {
    int e = (bt - 17) * 256 + t;
    if (e < EE) atomicAdd(&counts[edst[e]], 1);
  } else {
    int cb = bt - 17 - NB_HIST;          // 0..1249
    size_t base = (size_t)cb * 8192 + t * 4;
    #pragma unroll
    for (int j = 0; j < 8; ++j) {
      float4 v = *(const float4*)(x + base + j * 1024);
      bf16x4 o;
      o[0] = (__bf16)v.x; o[1] = (__bf16)v.y;
      o[2] = (__bf16)v.z; o[3] = (__bf16)v.w;
      *(bf16x4*)(xb + base + j * 1024) = o;
    }
  }
}

// ---------------------------------------------------------------------------
// 1-block scan of counts -> offsets, cursor. Counts staged through LDS so
// every global access is coalesced.
// ---------------------------------------------------------------------------
#define SCAN_PAD (79 * 256)   // 20224 >= NN
__global__ __launch_bounds__(256) void scan_kernel(
    const int* __restrict__ counts,
    int* __restrict__ offsets,
    int* __restrict__ cursor) {
  __shared__ int lc[SCAN_PAD];
  __shared__ int part[256];
  int t = threadIdx.x;
  for (int j = 0; j < 79; ++j) {
    int idx = j * 256 + t;
    lc[idx] = (idx < NN) ? counts[idx] : 0;
  }
  __syncthreads();
  int lo = t * 79;
  int s = 0;
  #pragma unroll 4
  for (int i = 0; i < 79; ++i) s += lc[lo + i];
  part[t] = s;
  __syncthreads();
  for (int off = 1; off < 256; off <<= 1) {
    int v = (t >= off) ? part[t - off] : 0;
    __syncthreads();
    part[t] += v;
    __syncthreads();
  }
  int base = (t == 0) ? 0 : part[t - 1];
  for (int i = 0; i < 79; ++i) {
    int c = lc[lo + i];
    lc[lo + i] = base;
    base += c;
  }
  if (t == 255) offsets[NN] = base;
  __syncthreads();
  for (int j = 0; j < 79; ++j) {
    int idx = j * 256 + t;
    if (idx < NN) {
      int v = lc[idx];
      offsets[idx] = v;
      cursor[idx]  = v;
    }
  }
}

// ---------------------------------------------------------------------------
// Fused scatter + edge-feature reduction: one pass over the edge list.
// ---------------------------------------------------------------------------
__global__ __launch_bounds__(256) void scatter_esum(
    const int* __restrict__ edst, const int* __restrict__ esrc,
    int* __restrict__ cursor,
    const float* __restrict__ edata, const float* __restrict__ wesum,
    int* __restrict__ ssrc, float* __restrict__ esum) {
  __shared__ float wl[512];
  int t = threadIdx.x;
  wl[t] = wesum[t];
  wl[t + 256] = wesum[t + 256];
  __syncthreads();
  int e = blockIdx.x * 256 + t;        // EE = 1250*256 exactly
  int p = atomicAdd(&cursor[edst[e]], 1);
  ssrc[p] = esrc[e];
  float acc[8] = {};
  const float* row = edata + (size_t)e * 64;
  for (int d = 0; d < 64; d += 4) {
    float4 v = *(const float4*)(row + d);
    #pragma unroll
    for (int hh = 0; hh < 8; ++hh) {
      const float* wv = &wl[hh * 64 + d];
      acc[hh] += v.x * wv[0] + v.y * wv[1] + v.z * wv[2] + v.w * wv[3];
    }
  }
  float* op = esum + (size_t)p * 8;
  *(float4*)op       = make_float4(acc[0], acc[1], acc[2], acc[3]);
  *(float4*)(op + 4) = make_float4(acc[4], acc[5], acc[6], acc[7]);
}

// ---------------------------------------------------------------------------
// Fused q|k|v|r GEMM (round-5 known-good config, 382 us total).
// A staged in LDS per K-step (BK=64, LSTR=72, 2-way banks = free); B read
// directly from L2 (wt = 0.5 MB resident). Tile 64x256, 4 waves, 4x4 frags.
// ---------------------------------------------------------------------------
__global__ __launch_bounds__(256) void gemm_qkvr(
    const __bf16* __restrict__ xb,   // [MROWS][256] bf16
    const __bf16* __restrict__ wt,   // [1024][256] bf16 (n-major, permuted)
    const float* __restrict__ bcat,  // [1024] permuted
    __hip_bfloat16* __restrict__ out) {  // [MROWS][1024] bf16 permuted
  const int LSTR = 72;
  __shared__ __attribute__((aligned(16))) __bf16 As[64 * LSTR];

  int m0 = blockIdx.y * 64;
  int n0 = blockIdx.x * 256;
  int t = threadIdx.x;
  int w = t >> 6, l = t & 63;
  int lr = l & 15, lq = l >> 4;
  int ar = t >> 2, ac = (t & 3) * 16;   // A staging: row, col (16 elems/thr)

  floatx4 acc[4][4] = {};               // [mt][nt]
  const __bf16* wbase = wt + (size_t)(n0 + 64 * w + lr) * 256 + lq * 8;

  for (int ks = 0; ks < 4; ++ks) {
    const __bf16* xp = xb + (size_t)(m0 + ar) * 256 + ks * 64 + ac;
    bf16x8 a0 = *(const bf16x8*)xp;
    bf16x8 a1 = *(const bf16x8*)(xp + 8);
    bf16x8 bfr[2][4];
    #pragma unroll
    for (int kk = 0; kk < 2; ++kk)
      #pragma unroll
      for (int nt = 0; nt < 4; ++nt)
        bfr[kk][nt] = *(const bf16x8*)(wbase + (size_t)nt * 16 * 256 + ks * 64 + kk * 32);
    __syncthreads();                    // previous step's frag reads done
    *(bf16x8*)&As[ar * LSTR + ac]     = a0;
    *(bf16x8*)&As[ar * LSTR + ac + 8] = a1;
    __syncthreads();
    #pragma unroll
    for (int kk = 0; kk < 2; ++kk) {
      bf16x8 af[4];
      #pragma unroll
      for (int mt = 0; mt < 4; ++mt)
        af[mt] = *(const bf16x8*)&As[(16 * mt + lr) * LSTR + kk * 32 + lq * 8];
      #pragma unroll
      for (int mt = 0; mt < 4; ++mt)
        #pragma unroll
        for (int nt = 0; nt < 4; ++nt)
          acc[mt][nt] = __builtin_amdgcn_mfma_f32_16x16x32_bf16(af[mt], bfr[kk][nt], acc[mt][nt], 0, 0, 0);
    }
  }

  // C/D: col = lane&15, row = (lane>>4)*4 + reg
  #pragma unroll
  for (int mt = 0; mt < 4; ++mt)
    #pragma unroll
    for (int nt = 0; nt < 4; ++nt)
      #pragma unroll
      for (int r = 0; r < 4; ++r) {
        int gr = m0 + 16 * mt + lq * 4 + r;
        int gc = n0 + 64 * w + 16 * nt + lr;
        out[(size_t)gr * 1024 + gc] = __float2bfloat16(acc[mt][nt][r] + bcat[gc]);
      }
}

// ---------------------------------------------------------------------------
// Fused logits + softmax + V-aggregation + residual, fp32 out.
// ONE WAVE per (dst,b); NEW lane layout: 4 lanes/head x 8 channels/lane
// (32 B = 2 dwordx4 per lane), so 32 lanes cover a kv row and the wave's
// two halves process TWO edges concurrently (half 0: edge i, half 1: edge
// i+32 of each 64-chunk). Head-reduce = 2 DPP quad_perm adds (pure VALU,
// NO ds_bpermute) — removes the ~300-cycle serial LDS-pipe chain that the
// old 3x shfl_xor paid per edge. Inactive (half,it) slots get es=-inf so
// p=exp(-inf)=0 and no accumulate guards are needed. Depth-4 pair pipeline.
// Cross-half merge: 9 shfl_xor(32) once per wave; half 0 stores.
// ---------------------------------------------------------------------------
__device__ __forceinline__ float quad_reduce(float x) {
  // xor1 (quad_perm [1,0,3,2] = 0xB1) + xor2 (quad_perm [2,3,0,1] = 0x4E)
  x += __int_as_float(__builtin_amdgcn_update_dpp(
      0, __float_as_int(x), 0xB1, 0xF, 0xF, true));
  x += __int_as_float(__builtin_amdgcn_update_dpp(
      0, __float_as_int(x), 0x4E, 0xF, 0xF, true));
  return x;
}

#define LOADSLOT(KA, KB, EV, IT)                                       \
  { int sa_ = __builtin_amdgcn_readlane(s_l, (IT));                    \
    int sb_ = __builtin_amdgcn_readlane(s_l, (IT) + 32);               \
    if ((IT) < cnt) {                                                  \
      const unsigned* p_ = kvl + (size_t)(half ? sb_ : sa_) * 1024;    \
      KA = *(const uint4*)p_;                                          \
      KB = *(const uint4*)(p_ + 4);                                    \
      EV = esp[(size_t)(IT) * 8];                                      \
    } }

#define RELOAD(KA, KB, EV, IT) { EV = -INFINITY; LOADSLOT(KA, KB, EV, IT) }

#define CONSUME(KA, KB, EV)                                            \
  { float part =                                                       \
      __uint_as_float(KA.x << 16) * q0 + __uint_as_float(KA.y << 16) * q1  \
    + __uint_as_float(KA.z << 16) * q2 + __uint_as_float(KA.w << 16) * q3  \
    + __uint_as_float(KB.x << 16) * q4 + __uint_as_float(KB.y << 16) * q5  \
    + __uint_as_float(KB.z << 16) * q6 + __uint_as_float(KB.w << 16) * q7; \
    part = quad_reduce(part);                                          \
    float p = __expf(part * 0.17677669529663687f + EV);                \
    z += p;                                                            \
    a0 += p * __uint_as_float(KA.x & 0xFFFF0000u);                     \
    a1 += p * __uint_as_float(KA.y & 0xFFFF0000u);                     \
    a2 += p * __uint_as_float(KA.z & 0xFFFF0000u);                     \
    a3 += p * __uint_as_float(KA.w & 0xFFFF0000u);                     \
    a4 += p * __uint_as_float(KB.x & 0xFFFF0000u);                     \
    a5 += p * __uint_as_float(KB.y & 0xFFFF0000u);                     \
    a6 += p * __uint_as_float(KB.z & 0xFFFF0000u);                     \
    a7 += p * __uint_as_float(KB.w & 0xFFFF0000u); }

__global__ __launch_bounds__(256) void aggregate_kernel(
    const unsigned int* __restrict__ qkvr,  // [MROWS][512] uints (kv | qr pairs)
    const float* __restrict__ esum,         // [E][8] CSR order
    const int* __restrict__ offsets,
    const int* __restrict__ ssrc,           // [E] src in CSR order
    float* __restrict__ out) {              // [MROWS][256] fp32
  int t = threadIdx.x;
  int w = t >> 6, l = t & 63;
  int nb = blockIdx.x * 4 + w;              // grid 10000 -> 40000 waves
  int b = nb & 1, n = nb >> 1;
  int half = l >> 5, u = l & 31;
  int h = u >> 2;                           // head 0..7
  int coff = h * 32 + (u & 3) * 8;          // channel base (uint units)
  int beg = offsets[n], end = offsets[n + 1];

  const unsigned* qrp = qkvr + (size_t)nb * 512 + 256 + coff;
  uint4 qa = *(const uint4*)qrp;
  uint4 qb = *(const uint4*)(qrp + 4);
  float q0 = __uint_as_float(qa.x << 16), q1 = __uint_as_float(qa.y << 16);
  float q2 = __uint_as_float(qa.z << 16), q3 = __uint_as_float(qa.w << 16);
  float q4 = __uint_as_float(qb.x << 16), q5 = __uint_as_float(qb.y << 16);
  float q6 = __uint_as_float(qb.z << 16), q7 = __uint_as_float(qb.w << 16);

  const unsigned* kvl = qkvr + (size_t)b * 512 + coff;   // + s*1024 per edge

  float z = 0.f;
  float a0 = 0.f, a1 = 0.f, a2 = 0.f, a3 = 0.f;
  float a4 = 0.f, a5 = 0.f, a6 = 0.f, a7 = 0.f;

  for (int base = beg; base < end; base += 64) {
    int chunk = min(64, end - base);
    int s_l = (l < chunk) ? ssrc[base + l] : 0;
    int itmax = chunk < 32 ? chunk : 32;            // wave-uniform
    int cnt = half ? chunk - 32 : itmax;            // per-half active count
    const float* esp = esum + ((size_t)base + (half ? 32 : 0)) * 8 + h;
    uint4 k0a = {0,0,0,0}, k0b = {0,0,0,0}, k1a = {0,0,0,0}, k1b = {0,0,0,0};
    uint4 k2a = {0,0,0,0}, k2b = {0,0,0,0}, k3a = {0,0,0,0}, k3b = {0,0,0,0};
    float e0 = -INFINITY, e1 = -INFINITY, e2 = -INFINITY, e3 = -INFINITY;
    LOADSLOT(k0a, k0b, e0, 0)
    LOADSLOT(k1a, k1b, e1, 1)
    LOADSLOT(k2a, k2b, e2, 2)
    LOADSLOT(k3a, k3b, e3, 3)
    for (int i = 0; i < itmax; i += 4) {
      CONSUME(k0a, k0b, e0)
      if (i + 4 < itmax) RELOAD(k0a, k0b, e0, i + 4)
      if (i + 1 < itmax) {
        CONSUME(k1a, k1b, e1)
        if (i + 5 < itmax) RELOAD(k1a, k1b, e1, i + 5)
        if (i + 2 < itmax) {
          CONSUME(k2a, k2b, e2)
          if (i + 6 < itmax) RELOAD(k2a, k2b, e2, i + 6)
          if (i + 3 < itmax) {
            CONSUME(k3a, k3b, e3)
            if (i + 7 < itmax) RELOAD(k3a, k3b, e3, i + 7)
          }
        }
      }
    }
  }

  // merge the two half-wave edge streams (once per wave)
  z  += __shfl_xor(z, 32, 64);
  a0 += __shfl_xor(a0, 32, 64);  a1 += __shfl_xor(a1, 32, 64);
  a2 += __shfl_xor(a2, 32, 64);  a3 += __shfl_xor(a3, 32, 64);
  a4 += __shfl_xor(a4, 32, 64);  a5 += __shfl_xor(a5, 32, 64);
  a6 += __shfl_xor(a6, 32, 64);  a7 += __shfl_xor(a7, 32, 64);

  if (half == 0) {
    float inv = (z > 0.f) ? (1.0f / z) : 0.f;
    float r0 = __uint_as_float(qa.x & 0xFFFF0000u);
    float r1 = __uint_as_float(qa.y & 0xFFFF0000u);
    float r2 = __uint_as_float(qa.z & 0xFFFF0000u);
    float r3 = __uint_as_float(qa.w & 0xFFFF0000u);
    float r4 = __uint_as_float(qb.x & 0xFFFF0000u);
    float r5 = __uint_as_float(qb.y & 0xFFFF0000u);
    float r6 = __uint_as_float(qb.z & 0xFFFF0000u);
    float r7 = __uint_as_float(qb.w & 0xFFFF0000u);
    float* op = out + (size_t)nb * 256 + coff;
    *(float4*)op       = make_float4(a0 * inv + r0, a1 * inv + r1,
                                     a2 * inv + r2, a3 * inv + r3);
    *(float4*)(op + 4) = make_float4(a4 * inv + r4, a5 * inv + r5,
                                     a6 * inv + r6, a7 * inv + r7);
  }
}

// ---------------------------------------------------------------------------
extern "C" void kernel_launch(void* const* d_in, const int* in_sizes, int n_in,
                              void* d_out, int out_size, void* d_ws, size_t ws_size,
                              hipStream_t stream) {
  (void)in_sizes; (void)n_in; (void)out_size; (void)ws_size;
  const float* x     = (const float*)d_in[0];
  const float* edata = (const float*)d_in[1];
  const int* esrc    = (const int*)d_in[2];
  const int* edst    = (const int*)d_in[3];
  const float* Wq    = (const float*)d_in[4];
  const float* bq    = (const float*)d_in[5];
  const float* Wk    = (const float*)d_in[6];
  const float* bk    = (const float*)d_in[7];
  const float* Wv    = (const float*)d_in[8];
  const float* bv    = (const float*)d_in[9];
  const float* We    = (const float*)d_in[10];
  const float* Wr    = (const float*)d_in[11];
  const float* br    = (const float*)d_in[12];
  float* out = (float*)d_out;     // fp32 output

  char* ws = (char*)d_ws;
  size_t off = 0;
  auto carve = [&](size_t bytes) -> void* {
    void* p = ws + off;
    off += (bytes + 255) & ~(size_t)255;
    return p;
  };
  int* counts    = (int*)carve((size_t)NN * 4);
  int* offsets   = (int*)carve((size_t)(NN + 1) * 4);
  int* cursor    = (int*)carve((size_t)NN * 4);
  int* ssrc      = (int*)carve((size_t)EE * 4);               // 1.28 MB
  __hip_bfloat16* wt = (__hip_bfloat16*)carve((size_t)1024 * 256 * 2);
  float* bcat    = (float*)carve(1024 * 4);
  float* wesum   = (float*)carve(8 * 64 * 4);
  float* esum    = (float*)carve((size_t)EE * 8 * 4);         // 10.24 MB
  __bf16* xb     = (__bf16*)carve((size_t)MROWS * 256 * 2);   // 20.5 MB
  __hip_bfloat16* qkvr = (__hip_bfloat16*)carve((size_t)MROWS * 1024 * 2); // 81.9 MB

  hipMemsetAsync(counts, 0, (size_t)NN * 4, stream);
  prep_kernel<<<17 + NB_HIST + NB_CVT, 256, 0, stream>>>(
      Wq, Wk, Wv, Wr, wt, bq, bk, bv, br, bcat, We, wesum, edst, counts, x, xb);
  scan_kernel<<<1, 256, 0, stream>>>(counts, offsets, cursor);
  scatter_esum<<<EE / 256, 256, 0, stream>>>(edst, esrc, cursor, edata, wesum,
                                             ssrc, esum);
  gemm_qkvr<<<dim3(4, 625), 256, 0, stream>>>(xb, (const __bf16*)wt, bcat, qkvr);
  aggregate_kernel<<<MROWS / 4, 256, 0, stream>>>((const unsigned int*)qkvr, esum,
                                                  offsets, ssrc, out);
}